// Round 14
// baseline (136.271 us; speedup 1.0000x reference)
//
#include <hip/hip_runtime.h>
#include <hip/hip_bf16.h>

// B=2,S=2048 -> T=4096 tokens; D=1024; N=64 experts; R=64; TOP_K=2.
// Inputs runtime-detected f32 vs bf16 (measured: f32). Outputs f32 flat:
// [0,262144) proj; [262144,270336) idx; [270336,278528) w.
// R14: score token-split 512 blocks x 8 tokens (M4E8/thread), 2 blocks/CU
// (R13 steady-state profile: score 60us @ 1 block/CU, VALUBusy 9% = exposed
// prefetch latency at barriers; TLP is the fix, extra dispatches are not -
// R11). Numerics bit-identical to R9/R13 (same k-partials + reduce tree,
// only thread ownership changes). egemm = R13 verbatim (b128 staging).
// d_ws: f32 w[t*2] (32KB); int cnt[64]; int list[64*1024] (256KB).

typedef unsigned short u16;
typedef unsigned int u32;
typedef __attribute__((ext_vector_type(8))) short short8;
typedef __attribute__((ext_vector_type(4))) float f32x4;

__device__ __forceinline__ float bf2f(u16 u) {
    u32 v = ((u32)u) << 16; float f; __builtin_memcpy(&f, &v, 4); return f;
}
__device__ __forceinline__ u16 f2bf(float f) {  // RNE
    u32 u; __builtin_memcpy(&u, &f, 4);
    u32 r = u + 0x7fff + ((u >> 16) & 1);
    return (u16)(r >> 16);
}
__device__ __forceinline__ u32 pack2(float a, float b) {
    return ((u32)f2bf(b) << 16) | (u32)f2bf(a);
}

#define T_TOKENS 4096
#define DDIM 1024
#define NEXP 64
#define RDIM 64
#define LCAP 1024
#define OUT_IDX_OFF 262144
#define OUT_W_OFF 270336

struct LdBF {
    const u16* p;
    __device__ __forceinline__ float4 ld4(size_t i) const {
        ushort4 v = *(const ushort4*)(p + i);
        return make_float4(bf2f(v.x), bf2f(v.y), bf2f(v.z), bf2f(v.w));
    }
    __device__ __forceinline__ float ld1(size_t i) const { return bf2f(p[i]); }
};
struct LdF32 {
    const float* p;
    __device__ __forceinline__ float4 ld4(size_t i) const { return *(const float4*)(p + i); }
    __device__ __forceinline__ float ld1(size_t i) const { return p[i]; }
};

// in-block dtype probe: 1 if f32, 0 if bf16 (all blocks same verdict).
__device__ __forceinline__ int detect_f32(const u16* x, int* lds_cnt) {
    if (threadIdx.x == 0) *lds_cnt = 0;
    __syncthreads();
    if (threadIdx.x < 256) {
        unsigned e = (x[threadIdx.x] >> 7) & 0xFF;
        if (e >= 0x68 && e <= 0x88) atomicAdd(lds_cnt, 1);
    }
    __syncthreads();
    int f = (*lds_cnt < 200) ? 1 : 0;
    __syncthreads();
    return f;
}

// ---------------- Kernel A: score GEMM + top2 + softmax + expert lists ----
// 512 blocks x 256 thr; 8 tokens/block; K-chunks of 64.
// Lane: tg=lane&1 (tokens tg+2mi, mi<4), eg=(lane>>1)&7 (experts eg+8ei),
// kql=(lane>>4)&3; k-quad dd = 4*kql + 16*wv. Per thread 4x8 acc.
// Per-(t,e) k-partials and reduce tree identical to R9/R13 (bit-exact).
template <class LD>
__device__ __forceinline__ void score_body(LD xld, LD rwld,
                                           float* xs /*8*68*/, float* wt /*64*68*/,
                                           float* sc /*8*65*/,
                                           float* out, float* wsW,
                                           int* wsCnt, int* wsList) {
    const int tid = threadIdx.x;
    const size_t t0 = (size_t)blockIdx.x * 8;
    const int wv = tid >> 6;
    const int lane = tid & 63;
    const int tg = lane & 1;
    const int eg = (lane >> 1) & 7;
    const int kql = (lane >> 4) & 3;
    const int dd = 4 * kql + 16 * wv;

    // zero this block's 8x64 proj out-region (egemm atomically accumulates)
    if (tid < 128) {
        float4 z = make_float4(0.f, 0.f, 0.f, 0.f);
        ((float4*)out)[(size_t)blockIdx.x * 128 + tid] = z;
    }

    const int sm = tid >> 4;            // x staging row (tid<128: 0..7)
    const int sd4 = (tid & 15) * 4;

    float acc[4][8];
#pragma unroll
    for (int mi = 0; mi < 4; ++mi)
#pragma unroll
        for (int ei = 0; ei < 8; ++ei) acc[mi][ei] = 0.f;

    float4 px;
    if (tid < 128) px = xld.ld4((t0 + sm) * DDIM + sd4);
    float4 pw[4];
#pragma unroll
    for (int h = 0; h < 4; ++h) {
        int i4 = tid + h * 256;
        pw[h] = rwld.ld4((size_t)(i4 >> 4) * DDIM + (i4 & 15) * 4);
    }

    for (int kc = 0; kc < 16; ++kc) {
        if (kc > 0) __syncthreads();
        if (tid < 128) *(float4*)&xs[sm * 68 + sd4] = px;
#pragma unroll
        for (int h = 0; h < 4; ++h) {
            int i4 = tid + h * 256;
            *(float4*)&wt[(i4 >> 4) * 68 + (i4 & 15) * 4] = pw[h];
        }
        __syncthreads();

        if (kc < 15) {
            if (tid < 128) px = xld.ld4((t0 + sm) * DDIM + (kc + 1) * 64 + sd4);
#pragma unroll
            for (int h = 0; h < 4; ++h) {
                int i4 = tid + h * 256;
                pw[h] = rwld.ld4((size_t)(i4 >> 4) * DDIM + (kc + 1) * 64 + (i4 & 15) * 4);
            }
        }

        float4 xv[4], wv4[8];
#pragma unroll
        for (int mi = 0; mi < 4; ++mi)
            xv[mi] = *(const float4*)&xs[(tg + 2 * mi) * 68 + dd];
#pragma unroll
        for (int ei = 0; ei < 8; ++ei)
            wv4[ei] = *(const float4*)&wt[(eg + 8 * ei) * 68 + dd];
#pragma unroll
        for (int mi = 0; mi < 4; ++mi)
#pragma unroll
            for (int ei = 0; ei < 8; ++ei)
                acc[mi][ei] += xv[mi].x * wv4[ei].x + xv[mi].y * wv4[ei].y +
                               xv[mi].z * wv4[ei].z + xv[mi].w * wv4[ei].w;
    }

    // in-wave k-quad reduce (deterministic tree over kql)
#pragma unroll
    for (int mi = 0; mi < 4; ++mi)
#pragma unroll
        for (int ei = 0; ei < 8; ++ei) {
            float v = acc[mi][ei];
            v += __shfl_xor(v, 16, 64);
            v += __shfl_xor(v, 32, 64);
            acc[mi][ei] = v;
        }
    __syncthreads();

    // cross-wave reduce: sequential wave phases (deterministic order)
    for (int w = 0; w < 4; ++w) {
        if (wv == w && kql == 0) {
#pragma unroll
            for (int mi = 0; mi < 4; ++mi)
#pragma unroll
                for (int ei = 0; ei < 8; ++ei) {
                    int idx = (tg + 2 * mi) * 65 + eg + 8 * ei;
                    sc[idx] = (w == 0) ? acc[mi][ei] : sc[idx] + acc[mi][ei];
                }
        }
        __syncthreads();
    }

    if (tid < 8) {
        const float* s = &sc[tid * 65];
        float best = -1e30f, secv = -1e30f;
        int bi = 0, si = 0;
        for (int j = 0; j < NEXP; ++j) {
            float v = s[j];
            if (v > best) { secv = best; si = bi; best = v; bi = j; }
            else if (v > secv) { secv = v; si = j; }
        }
        float w0 = 1.0f / (1.0f + expf(secv - best));
        float w1 = 1.0f - w0;
        size_t t = t0 + tid;
        out[OUT_IDX_OFF + t * 2 + 0] = (float)bi;
        out[OUT_IDX_OFF + t * 2 + 1] = (float)si;
        out[OUT_W_OFF + t * 2 + 0] = w0;
        out[OUT_W_OFF + t * 2 + 1] = w1;
        wsW[t * 2 + 0] = w0;
        wsW[t * 2 + 1] = w1;
        int p0 = atomicAdd(&wsCnt[bi], 1);
        if (p0 < LCAP) wsList[bi * LCAP + p0] = (int)(t * 2 + 0);
        int p1 = atomicAdd(&wsCnt[si], 1);
        if (p1 < LCAP) wsList[si * LCAP + p1] = (int)(t * 2 + 1);
    }
}

__global__ __launch_bounds__(256, 2) void score_topk(const void* x, const void* rw,
                                                     float* out, float* wsW,
                                                     int* wsCnt, int* wsList) {
    __shared__ float xs[8 * 68];
    __shared__ float wt[64 * 68];
    __shared__ float sc[8 * 65];
    __shared__ int dc;
    int f = detect_f32((const u16*)x, &dc);
    if (f)
        score_body(LdF32{(const float*)x}, LdF32{(const float*)rw}, xs, wt, sc, out, wsW, wsCnt, wsList);
    else
        score_body(LdBF{(const u16*)x}, LdBF{(const u16*)rw}, xs, wt, sc, out, wsW, wsCnt, wsList);
}

// ---------------- Kernel B: per-expert bf16 MFMA GEMM (R13 verbatim) -------
// 1024 blocks: e = bid&63 (XCD = e%8), ti = bid>>6 (rows [16ti,16ti+16)).
template <class LD>
__device__ __forceinline__ void egemm_body(LD xld, LD nld,
                                           const int* wsCnt, const int* wsList,
                                           const float* wsW, float* out,
                                           u16* Ab /*16*136*/, u16* Bb /*64*136*/,
                                           int* entL /*16*/) {
    const int tid = threadIdx.x;
    const int e = blockIdx.x & 63;
    const int ti = blockIdx.x >> 6;
    const int cntE = min(wsCnt[e], LCAP);
    const int base = ti * 16;
    if (base >= cntE) return;
    const int valid = min(16, cntE - base);
    const int wv = tid >> 6;
    const int lane = tid & 63;
    const int l15 = lane & 15, quad = lane >> 4;
    const size_t nbase = (size_t)e * (DDIM * RDIM);

    if (tid < 16)
        entL[tid] = wsList[e * LCAP + base + min(tid, valid - 1)];
    __syncthreads();

    const int rowA = tid & 15;
    const int kq0 = tid >> 4;
    const size_t ttA = (size_t)(entL[rowA] >> 1) * DDIM;

    f32x4 acc = {0.f, 0.f, 0.f, 0.f};

    for (int kc = 0; kc < 8; ++kc) {
        const int k0c = kc * 128;
        if (kc > 0) __syncthreads();
#pragma unroll
        for (int h = 0; h < 4; ++h) {
            int u = tid + h * 256;
            int rq = u & 15, kp = u >> 4;
            float4 g0 = nld.ld4(nbase + (size_t)(k0c + 2 * kp) * RDIM + 4 * rq);
            float4 g1 = nld.ld4(nbase + (size_t)(k0c + 2 * kp + 1) * RDIM + 4 * rq);
            u32* bw = (u32*)Bb;
            bw[(4 * rq + 0) * 68 + kp] = pack2(g0.x, g1.x);
            bw[(4 * rq + 1) * 68 + kp] = pack2(g0.y, g1.y);
            bw[(4 * rq + 2) * 68 + kp] = pack2(g0.z, g1.z);
            bw[(4 * rq + 3) * 68 + kp] = pack2(g0.w, g1.w);
        }
        {
            float4 ga0 = xld.ld4(ttA + k0c + 4 * kq0);
            float4 ga1 = xld.ld4(ttA + k0c + 4 * (kq0 + 16));
            u32* aw = (u32*)Ab;
            aw[rowA * 68 + 2 * kq0 + 0]  = pack2(ga0.x, ga0.y);
            aw[rowA * 68 + 2 * kq0 + 1]  = pack2(ga0.z, ga0.w);
            aw[rowA * 68 + 2 * kq0 + 32] = pack2(ga1.x, ga1.y);
            aw[rowA * 68 + 2 * kq0 + 33] = pack2(ga1.z, ga1.w);
        }
        __syncthreads();

#pragma unroll
        for (int ko = 0; ko < 4; ++ko) {
            int kofs = ko * 32 + quad * 8;
            short8 bfr = *(const short8*)&Bb[(16 * wv + l15) * 136 + kofs];
            short8 af = *(const short8*)&Ab[l15 * 136 + kofs];
            acc = __builtin_amdgcn_mfma_f32_16x16x32_bf16(af, bfr, acc, 0, 0, 0);
        }
    }

    // D: row (token m) = quad*4+reg, col r = 16*wv + l15
#pragma unroll
    for (int reg = 0; reg < 4; ++reg) {
        int m = quad * 4 + reg;
        if (m < valid) {
            int t2 = entL[m];
            atomicAdd(&out[(size_t)(t2 >> 1) * RDIM + 16 * wv + l15], wsW[t2] * acc[reg]);
        }
    }
}

__global__ __launch_bounds__(256) void expert_gemm(const void* x, const void* neurons,
                                                   const int* wsCnt, const int* wsList,
                                                   const float* wsW, float* out) {
    __shared__ u16 Ab[16 * 136];
    __shared__ u16 Bb[64 * 136];
    __shared__ int entL[16];
    __shared__ int dc;
    int f = detect_f32((const u16*)x, &dc);
    if (f)
        egemm_body(LdF32{(const float*)x}, LdF32{(const float*)neurons}, wsCnt, wsList, wsW, out, Ab, Bb, entL);
    else
        egemm_body(LdBF{(const u16*)x}, LdBF{(const u16*)neurons}, wsCnt, wsList, wsW, out, Ab, Bb, entL);
}

extern "C" void kernel_launch(void* const* d_in, const int* in_sizes, int n_in,
                              void* d_out, int out_size, void* d_ws, size_t ws_size,
                              hipStream_t stream) {
    const void* x = d_in[0];
    const void* rw = d_in[1];
    const void* neurons = d_in[2];
    float* out = (float*)d_out;

    char* wsc = (char*)d_ws;
    float* wsW = (float*)wsc;                                  // 32 KB
    int* wsCnt = (int*)(wsc + 32 * 1024);                      // 256 B
    int* wsList = (int*)((char*)wsCnt + 256);                  // 256 KB

    hipMemsetAsync(wsCnt, 0, 256, stream);
    score_topk<<<512, 256, 0, stream>>>(x, rw, out, wsW, wsCnt, wsList);
    expert_gemm<<<1024, 256, 0, stream>>>(x, neurons, wsCnt, wsList, wsW, out);
}